// Round 1
// baseline (50.706 us; speedup 1.0000x reference)
//
#include <hip/hip_runtime.h>
#include <math.h>

constexpr int IN_C = 31;
constexpr int TOT  = 44;
constexpr int HW   = 256 * 256;
constexpr int NPIX = 4 * HW;
constexpr float SMIN = 0.001f, SMAX = 1000.0f;
constexpr float PI_F = 3.14159265358979323846f;

// One thread per pixel. 256 threads/block = 4 waves; per-wave 16KB LDS staging
// buffer for coalesced S writes (wave-synchronous, no __syncthreads needed).
__global__ __launch_bounds__(256) void sepgpd_fused(
    const float* __restrict__ x,
    const float* __restrict__ Wenc,
    const float* __restrict__ benc,
    float* __restrict__ out)
{
    __shared__ float sbuf[4 * 4096];   // 64 KB: 4 waves x 64 pixels x 64 floats

    const int tid  = threadIdx.x;
    const int lane = tid & 63;
    const int wid  = tid >> 6;
    const int pix  = blockIdx.x * 256 + tid;   // grid exactly covers NPIX
    const int b    = pix >> 16;                // HW = 65536
    const int hw   = pix & (HW - 1);

    const float* xb = x + (size_t)b * IN_C * HW + hw;

    // ---- 44x31 GEMV (weights via scalar cache: uniform indices) ----
    float acc[TOT];
#pragma unroll
    for (int o = 0; o < TOT; ++o) acc[o] = benc[o];

#pragma unroll
    for (int c = 0; c < IN_C; ++c) {
        const float xc = xb[(size_t)c * HW];   // coalesced across lanes
#pragma unroll
        for (int o = 0; o < TOT; ++o)
            acc[o] = fmaf(xc, Wenc[o * IN_C + c], acc[o]);
    }

    // ---- m: first 8 channels, per-pixel contiguous ----
    float4* mp = reinterpret_cast<float4*>(out + (size_t)pix * 8);
    mp[0] = make_float4(acc[0], acc[1], acc[2], acc[3]);
    mp[1] = make_float4(acc[4], acc[5], acc[6], acc[7]);

    // ---- sqrt of scales: S = (sqrtD R)^T (sqrtD R) is exactly symmetric ----
    float sq[8];
#pragma unroll
    for (int j = 0; j < 8; ++j) {
        const float sig = 1.0f / (1.0f + __expf(-acc[8 + j]));
        const float s   = SMIN + (SMAX - SMIN) * sig;
        sq[j] = sqrtf(s);
    }

    // ---- R: product of Givens rotations applied to identity ----
    float R[8][8];
#pragma unroll
    for (int i = 0; i < 8; ++i)
#pragma unroll
        for (int k = 0; k < 8; ++k) R[i][k] = (i == k) ? 1.0f : 0.0f;

    int cc = 0;
#pragma unroll
    for (int i = 0; i < 7; ++i) {
#pragma unroll
        for (int j = i + 1; j < 8; ++j) {
            const float wv = acc[16 + cc];
            // tanh via exp, saturates correctly at +/-1 for large |wv|
            const float th = 1.0f - 2.0f / (__expf(2.0f * wv) + 1.0f);
            const float a  = PI_F * th;
            const float cs = __cosf(a);
            const float ss = __sinf(a);
#pragma unroll
            for (int r = 0; r < 8; ++r) {   // row-local column update
                const float ri = R[r][i];
                const float rj = R[r][j];
                R[r][i] = fmaf(ri, cs, rj * ss);
                R[r][j] = fmaf(rj, cs, -(ri * ss));
            }
            ++cc;
        }
    }

    // scale row j by sqrt(s_j)
#pragma unroll
    for (int j = 0; j < 8; ++j)
#pragma unroll
        for (int k = 0; k < 8; ++k) R[j][k] *= sq[j];

    // ---- S[i][k] = dot(col_i, col_k), symmetric ----
    float S[8][8];
#pragma unroll
    for (int i = 0; i < 8; ++i) {
#pragma unroll
        for (int k = i; k < 8; ++k) {
            float d = 0.0f;
#pragma unroll
            for (int j = 0; j < 8; ++j) d = fmaf(R[j][i], R[j][k], d);
            S[i][k] = d;
            S[k][i] = d;
        }
    }

    // ---- stage S into per-wave LDS with XOR swizzle (bank-conflict free) ----
    // float4 index v of pixel `lane` lives at float4-addr: lane*16 + (v ^ (lane&7))
    float* wbuf = sbuf + wid * 4096;
#pragma unroll
    for (int i = 0; i < 8; ++i) {
        const int v0 = i * 2;
        const int v1 = v0 + 1;
        const int a0 = lane * 64 + ((v0 ^ (lane & 7)) << 2);
        const int a1 = lane * 64 + ((v1 ^ (lane & 7)) << 2);
        *reinterpret_cast<float4*>(wbuf + a0) =
            make_float4(S[i][0], S[i][1], S[i][2], S[i][3]);
        *reinterpret_cast<float4*>(wbuf + a1) =
            make_float4(S[i][4], S[i][5], S[i][6], S[i][7]);
    }

    // ---- coalesced flush: 16 iters x 1KB/instruction ----
    const float4* rbuf = reinterpret_cast<const float4*>(wbuf);
    float4* S4 = reinterpret_cast<float4*>(out + (size_t)NPIX * 8);
    const size_t gbase = (size_t)(blockIdx.x * 256 + wid * 64) * 16;
#pragma unroll
    for (int k = 0; k < 16; ++k) {
        const int t  = k * 64 + lane;        // contiguous float4s
        const int pl = t >> 4;               // local pixel
        const int v  = t & 15;               // float4 index within pixel
        S4[gbase + t] = rbuf[pl * 16 + (v ^ (pl & 7))];
    }
}

extern "C" void kernel_launch(void* const* d_in, const int* in_sizes, int n_in,
                              void* d_out, int out_size, void* d_ws, size_t ws_size,
                              hipStream_t stream)
{
    const float* x    = (const float*)d_in[0];
    const float* Wenc = (const float*)d_in[1];
    const float* benc = (const float*)d_in[2];
    float* out        = (float*)d_out;

    dim3 grid(NPIX / 256), block(256);
    sepgpd_fused<<<grid, block, 0, stream>>>(x, Wenc, benc, out);
}

// Round 2
// 46.913 us; speedup vs baseline: 1.0809x; 1.0809x over previous
//
#include <hip/hip_runtime.h>
#include <math.h>

constexpr int IN_C = 31;
constexpr int TOT  = 44;
constexpr int HW   = 256 * 256;
constexpr int NPIX = 4 * HW;
constexpr float SMIN = 0.001f, SMAX = 1000.0f;
constexpr float PI_F = 3.14159265358979323846f;

// One thread per pixel. 256 threads/block = 4 waves.
// S is flushed in TWO wave-synchronous phases through an 8KB-per-wave LDS
// staging buffer (reused across phases) -> 32KB/block -> 5 blocks/CU
// (20 waves/CU) instead of the 2 blocks/CU a 64KB buffer allowed.
__global__ __launch_bounds__(256) void sepgpd_fused(
    const float* __restrict__ x,
    const float* __restrict__ Wenc,
    const float* __restrict__ benc,
    float* __restrict__ out)
{
    __shared__ float sbuf[4][2048];   // 32 KB: 4 waves x 64 pixels x 32 floats

    const int tid  = threadIdx.x;
    const int lane = tid & 63;
    const int wid  = tid >> 6;
    const int pix  = blockIdx.x * 256 + tid;   // grid exactly covers NPIX
    const int b    = pix >> 16;                // HW = 65536
    const int hw   = pix & (HW - 1);

    const float* xb = x + (size_t)b * IN_C * HW + hw;

    // ---- 44x31 GEMV (weights via scalar cache: uniform indices) ----
    float acc[TOT];
#pragma unroll
    for (int o = 0; o < TOT; ++o) acc[o] = benc[o];

#pragma unroll
    for (int c = 0; c < IN_C; ++c) {
        const float xc = xb[(size_t)c * HW];   // coalesced across lanes
#pragma unroll
        for (int o = 0; o < TOT; ++o)
            acc[o] = fmaf(xc, Wenc[o * IN_C + c], acc[o]);
    }

    // ---- m: first 8 channels, per-pixel contiguous (coalesced) ----
    float4* mp = reinterpret_cast<float4*>(out + (size_t)pix * 8);
    mp[0] = make_float4(acc[0], acc[1], acc[2], acc[3]);
    mp[1] = make_float4(acc[4], acc[5], acc[6], acc[7]);

    // ---- sqrt of scales: S = (sqrtD R)^T (sqrtD R) is exactly symmetric ----
    float sq[8];
#pragma unroll
    for (int j = 0; j < 8; ++j) {
        const float sig = 1.0f / (1.0f + __expf(-acc[8 + j]));
        const float s   = SMIN + (SMAX - SMIN) * sig;
        sq[j] = sqrtf(s);
    }

    // ---- R: product of Givens rotations applied to identity ----
    float R[8][8];
#pragma unroll
    for (int i = 0; i < 8; ++i)
#pragma unroll
        for (int k = 0; k < 8; ++k) R[i][k] = (i == k) ? 1.0f : 0.0f;

    int cc = 0;
#pragma unroll
    for (int i = 0; i < 7; ++i) {
#pragma unroll
        for (int j = i + 1; j < 8; ++j) {
            const float wv = acc[16 + cc];
            // tanh via exp, saturates correctly at +/-1 for large |wv|
            const float th = 1.0f - 2.0f / (__expf(2.0f * wv) + 1.0f);
            const float a  = PI_F * th;
            const float cs = __cosf(a);
            const float ss = __sinf(a);
#pragma unroll
            for (int r = 0; r < 8; ++r) {   // row-local column update
                const float ri = R[r][i];
                const float rj = R[r][j];
                R[r][i] = fmaf(ri, cs, rj * ss);
                R[r][j] = fmaf(rj, cs, -(ri * ss));
            }
            ++cc;
        }
    }

    // scale row j by sqrt(s_j)
#pragma unroll
    for (int j = 0; j < 8; ++j)
#pragma unroll
        for (int k = 0; k < 8; ++k) R[j][k] *= sq[j];

    // ---- S[i][k] = dot(col_i, col_k), symmetric ----
    float S[8][8];
#pragma unroll
    for (int i = 0; i < 8; ++i) {
#pragma unroll
        for (int k = i; k < 8; ++k) {
            float d = 0.0f;
#pragma unroll
            for (int j = 0; j < 8; ++j) d = fmaf(R[j][i], R[j][k], d);
            S[i][k] = d;
            S[k][i] = d;
        }
    }

    // ---- two-phase staged flush of S (wave-synchronous, buffer reused) ----
    // Phase p stages rows 4p..4p+3 (32 floats/pixel). Lane stride = 8 float4s,
    // swizzle (v ^ (lane&7)) keeps both write and read phases conflict-free.
    float* wbuf = &sbuf[wid][0];
    float4* wbuf4 = reinterpret_cast<float4*>(wbuf);
    float4* S4 = reinterpret_cast<float4*>(out + (size_t)NPIX * 8);
    const size_t pixbase4 = (size_t)(blockIdx.x * 256 + wid * 64) * 16; // float4s

#pragma unroll
    for (int p = 0; p < 2; ++p) {
        // stage rows 4p .. 4p+3
#pragma unroll
        for (int r = 0; r < 4; ++r) {
            const int i  = 4 * p + r;
            const int v0 = r * 2;
            const int v1 = v0 + 1;
            wbuf4[lane * 8 + (v0 ^ (lane & 7))] =
                make_float4(S[i][0], S[i][1], S[i][2], S[i][3]);
            wbuf4[lane * 8 + (v1 ^ (lane & 7))] =
                make_float4(S[i][4], S[i][5], S[i][6], S[i][7]);
        }
        // flush: 8 iters x 64 lanes; pixel pl's half-S occupies 8 float4s at
        // global float4 addr (pixbase+pl)*16 + p*8 + v  (128B-aligned chunks)
#pragma unroll
        for (int k = 0; k < 8; ++k) {
            const int t  = k * 64 + lane;
            const int pl = t >> 3;           // local pixel 0..63
            const int v  = t & 7;            // float4 index within half
            S4[pixbase4 + (size_t)pl * 16 + p * 8 + v] =
                wbuf4[pl * 8 + (v ^ (pl & 7))];
        }
    }
}

extern "C" void kernel_launch(void* const* d_in, const int* in_sizes, int n_in,
                              void* d_out, int out_size, void* d_ws, size_t ws_size,
                              hipStream_t stream)
{
    const float* x    = (const float*)d_in[0];
    const float* Wenc = (const float*)d_in[1];
    const float* benc = (const float*)d_in[2];
    float* out        = (float*)d_out;

    dim3 grid(NPIX / 256), block(256);
    sepgpd_fused<<<grid, block, 0, stream>>>(x, Wenc, benc, out);
}